// Round 8
// baseline (329.894 us; speedup 1.0000x reference)
//
#include <hip/hip_runtime.h>
#include <hip/hip_bf16.h>

#define N_NODES 50000
#define N_EDGES 600000
#define D_IN 256
#define D 128

#define SCAN_CHUNK 1024
#define N_CHUNKS ((N_NODES + SCAN_CHUNK - 1) / SCAN_CHUNK)  // 49

typedef unsigned short ushort_t;
typedef __attribute__((ext_vector_type(8))) short bf16x8;
typedef __attribute__((ext_vector_type(16))) float f32x16;

__device__ __forceinline__ float bf2f(ushort_t u) {
  union { unsigned int i; float f; } v;
  v.i = ((unsigned int)u) << 16;
  return v.f;
}
__device__ __forceinline__ ushort_t f2bf(float f) {
  union { float f; unsigned int i; } v;
  v.f = f;
  unsigned int x = v.i;
  unsigned int r = (x + 0x7FFFu + ((x >> 16) & 1u)) >> 16;  // RNE
  return (ushort_t)r;
}

// ---------------- dtype detection (insurance; expected all-fp32) ----------------
__global__ void k_detect(const void* e, const void* wn, const void* bn,
                         const void* w1, const void* b1, const void* w2,
                         const void* b2, int* flags) {
  const void* ptrs[7] = {e, wn, bn, w1, b1, w2, b2};
  const int ns[7] = {12800000, 32768, 128, 16384, 128, 16384, 128};
  __shared__ int red[256];
  int t = threadIdx.x;
  for (int a = 0; a < 7; a++) {
    int pn = ns[a] < 2048 ? ns[a] : 2048;
    const ushort_t* p = (const ushort_t*)ptrs[a];
    int cnt = 0;
    for (int i = t; i < pn; i += 256) {
      ushort_t u = p[i];
      int ex = (u >> 7) & 0xFF;
      if ((u & 0x7FFF) == 0 || (ex >= 100 && ex <= 130)) cnt++;
    }
    red[t] = cnt;
    __syncthreads();
    for (int off = 128; off > 0; off >>= 1) {
      if (t < off) red[t] += red[t + off];
      __syncthreads();
    }
    if (t == 0) flags[a] = (red[0] * 100 >= pn * 85) ? 1 : 0;
    __syncthreads();
  }
}

// Split weights into bf16 hi/lo; canonicalize biases to fp32 ws.
__global__ void k_split(const void* wn, const void* w1, const void* w2,
                        const void* bn, const void* b1, const void* b2,
                        const int* __restrict__ flags,
                        ushort_t* __restrict__ WnH, ushort_t* __restrict__ WnL,
                        ushort_t* __restrict__ w1H, ushort_t* __restrict__ w1L,
                        ushort_t* __restrict__ w2H, ushort_t* __restrict__ w2L,
                        float* __restrict__ bias_ws) {
  int i = blockIdx.x * blockDim.x + threadIdx.x;
  if (i >= 65920) return;
  if (i < 65536) {
    const void* src; int j; int fl; ushort_t *H, *L;
    if (i < 32768)      { src = wn; j = i;         fl = flags[1]; H = WnH; L = WnL; }
    else if (i < 49152) { src = w1; j = i - 32768; fl = flags[3]; H = w1H; L = w1L; }
    else                { src = w2; j = i - 49152; fl = flags[5]; H = w2H; L = w2L; }
    float v = fl ? bf2f(((const ushort_t*)src)[j]) : ((const float*)src)[j];
    ushort_t h = f2bf(v);
    H[j] = h;
    L[j] = f2bf(v - bf2f(h));
  } else {
    const void* src; int j; int fl;
    if (i < 65664)      { src = bn; j = i - 65536; fl = flags[2]; }
    else if (i < 65792) { src = b1; j = i - 65664; fl = flags[4]; }
    else                { src = b2; j = i - 65792; fl = flags[6]; }
    bias_ws[i - 65536] = fl ? bf2f(((const ushort_t*)src)[j]) : ((const float*)src)[j];
  }
}

// ---------------- CSR build ----------------

__global__ void k_deg(const int* __restrict__ dst, int* __restrict__ deg) {
  int e = blockIdx.x * blockDim.x + threadIdx.x;
  if (e < N_EDGES) atomicAdd(&deg[dst[e]], 1);
}

__global__ void k_partial(const int* __restrict__ deg, int* __restrict__ partial) {
  __shared__ int lds[256];
  int b = blockIdx.x, t = threadIdx.x;
  int base = b * SCAN_CHUNK + t * 4;
  int s = 0;
#pragma unroll
  for (int i = 0; i < 4; i++) {
    int idx = base + i;
    if (idx < N_NODES) s += deg[idx];
  }
  lds[t] = s;
  __syncthreads();
  for (int off = 128; off > 0; off >>= 1) {
    if (t < off) lds[t] += lds[t + off];
    __syncthreads();
  }
  if (t == 0) partial[b] = lds[0];
}

__global__ void k_scan_part(int* __restrict__ partial, int* __restrict__ row_start) {
  if (threadIdx.x == 0) {
    int run = 0;
    for (int i = 0; i < N_CHUNKS; i++) {
      int v = partial[i];
      partial[i] = run;
      run += v;
    }
    row_start[N_NODES] = run;
  }
}

__global__ void k_scan_final(const int* __restrict__ deg, const int* __restrict__ partial,
                             int* __restrict__ row_start, float* __restrict__ dinv) {
  __shared__ int lds[256];
  int b = blockIdx.x, t = threadIdx.x;
  int base = b * SCAN_CHUNK + t * 4;
  int v[4];
  int s = 0;
#pragma unroll
  for (int i = 0; i < 4; i++) {
    int idx = base + i;
    v[i] = (idx < N_NODES) ? deg[idx] : 0;
    s += v[i];
  }
  lds[t] = s;
  __syncthreads();
  for (int off = 1; off < 256; off <<= 1) {
    int add = (t >= off) ? lds[t - off] : 0;
    __syncthreads();
    lds[t] += add;
    __syncthreads();
  }
  int excl = lds[t] - s + partial[b];
#pragma unroll
  for (int i = 0; i < 4; i++) {
    int idx = base + i;
    if (idx < N_NODES) {
      row_start[idx] = excl;
      dinv[idx] = rsqrtf((float)(v[i] + 1));  // +1 self-loop
      excl += v[i];
    }
  }
}

__global__ void k_fill(const int* __restrict__ src, const int* __restrict__ dst,
                       const int* __restrict__ row_start, int* __restrict__ cursor,
                       int* __restrict__ csr) {
  int e = blockIdx.x * blockDim.x + threadIdx.x;
  if (e < N_EDGES) {
    int d = dst[e];
    int pos = atomicAdd(&cursor[d], 1);
    csr[row_start[d] + pos] = src[e];
  }
}

// ---------------- MFMA split-bf16 GEMM v2 ----------------
// out[n][j] = sum_k X[n][k] W[j][k] (+bias).  acc = Xh*Wh + Xh*Wl + Xl*Wh.
// Block: 32 nodes x 128 j, 4 waves; wave wv owns j in [32wv, 32wv+32).
// W slice lives in 64 VGPRs (loaded from L2, no LDS, no barrier);
// X tile staged once per 128-K pass -> ONE barrier per pass, then
// 24 MFMAs + 16 ds_read_b128 barrier-free.
template <int KDIM, bool EMBED>
__global__ __launch_bounds__(256) void k_gemm_v2(
    const ushort_t* __restrict__ Xh, const ushort_t* __restrict__ Xl,
    const void* __restrict__ Xv, const int* __restrict__ tokens,
    const int* __restrict__ flags,
    const ushort_t* __restrict__ Wh, const ushort_t* __restrict__ Wl,
    const float* __restrict__ bias, const float* __restrict__ dinvp,
    ushort_t* __restrict__ OutH, ushort_t* __restrict__ OutL,
    ushort_t* __restrict__ OutT) {
  constexpr int XS = 136;  // LDS row stride (ushorts): 272 B, 16B-aligned rows
  __shared__ __align__(16) ushort_t xh_lds[32 * XS];
  __shared__ __align__(16) ushort_t xl_lds[32 * XS];

  int tid = threadIdx.x;
  int lane = tid & 63;
  int wv = tid >> 6;
  int node0 = blockIdx.x * 32;
  int fm = lane & 31;
  int fq = lane >> 5;

  int fl = EMBED ? flags[0] : 0;

  f32x16 acc;
#pragma unroll
  for (int r = 0; r < 16; r++) acc[r] = 0.f;

#pragma unroll
  for (int kh = 0; kh < KDIM / 128; kh++) {
    if (kh) __syncthreads();  // all waves done reading LDS of prev pass
    // ---- stage X tile: 32 rows x 128 cols, hi/lo split, 4 segs/thread ----
    if (EMBED) {
      int rows[4], c4s[4];
      if (fl) {
        ushort4 v[4];
#pragma unroll
        for (int i = 0; i < 4; i++) {
          int seg = tid + 256 * i;
          rows[i] = seg >> 5; c4s[i] = seg & 31;
          int tk = tokens[min(node0 + rows[i], N_NODES - 1)];
          v[i] = *(const ushort4*)&(
              (const ushort_t*)Xv)[(size_t)tk * KDIM + kh * 128 + 4 * c4s[i]];
        }
        ushort4 z; z.x = 0; z.y = 0; z.z = 0; z.w = 0;
#pragma unroll
        for (int i = 0; i < 4; i++) {
          *(ushort4*)&xh_lds[rows[i] * XS + 4 * c4s[i]] = v[i];
          *(ushort4*)&xl_lds[rows[i] * XS + 4 * c4s[i]] = z;
        }
      } else {
        float4 v[4];
#pragma unroll
        for (int i = 0; i < 4; i++) {
          int seg = tid + 256 * i;
          rows[i] = seg >> 5; c4s[i] = seg & 31;
          int tk = tokens[min(node0 + rows[i], N_NODES - 1)];
          v[i] = *(const float4*)&(
              (const float*)Xv)[(size_t)tk * KDIM + kh * 128 + 4 * c4s[i]];
        }
#pragma unroll
        for (int i = 0; i < 4; i++) {
          ushort4 h, l;
          h.x = f2bf(v[i].x); l.x = f2bf(v[i].x - bf2f(h.x));
          h.y = f2bf(v[i].y); l.y = f2bf(v[i].y - bf2f(h.y));
          h.z = f2bf(v[i].z); l.z = f2bf(v[i].z - bf2f(h.z));
          h.w = f2bf(v[i].w); l.w = f2bf(v[i].w - bf2f(h.w));
          *(ushort4*)&xh_lds[rows[i] * XS + 4 * c4s[i]] = h;
          *(ushort4*)&xl_lds[rows[i] * XS + 4 * c4s[i]] = l;
        }
      }
    } else {
      uint4 v[4];
      int rows[4], scs[4], isl[4];
#pragma unroll
      for (int i = 0; i < 4; i++) {
        int seg = tid + 256 * i;  // 0..1023; first 512 = H, rest = L
        int hseg = seg & 511;
        rows[i] = hseg >> 4; scs[i] = hseg & 15; isl[i] = seg >> 9;
        const ushort_t* srcp = isl[i] ? Xl : Xh;
        int n = min(node0 + rows[i], N_NODES - 1);
        v[i] = *(const uint4*)&srcp[(size_t)n * KDIM + kh * 128 + 8 * scs[i]];
      }
#pragma unroll
      for (int i = 0; i < 4; i++) {
        ushort_t* dst = isl[i] ? xl_lds : xh_lds;
        *(uint4*)&dst[rows[i] * XS + 8 * scs[i]] = v[i];
      }
    }
    // ---- W fragments for this K-half into VGPRs (overlaps barrier drain) ----
    bf16x8 wbh[8], wbl[8];
    {
      int j = wv * 32 + fm;
      const ushort_t* ph = &Wh[(size_t)j * KDIM + kh * 128 + fq * 8];
      const ushort_t* pl = &Wl[(size_t)j * KDIM + kh * 128 + fq * 8];
#pragma unroll
      for (int t = 0; t < 8; t++) {
        wbh[t] = *(const bf16x8*)(ph + t * 16);
        wbl[t] = *(const bf16x8*)(pl + t * 16);
      }
    }
    __syncthreads();
    // ---- compute: 8 K-steps of 16, barrier-free ----
#pragma unroll
    for (int t = 0; t < 8; t++) {
      int ko = t * 16 + fq * 8;
      bf16x8 ah = *(const bf16x8*)&xh_lds[fm * XS + ko];
      bf16x8 al = *(const bf16x8*)&xl_lds[fm * XS + ko];
      acc = __builtin_amdgcn_mfma_f32_32x32x16_bf16(ah, wbh[t], acc, 0, 0, 0);
      acc = __builtin_amdgcn_mfma_f32_32x32x16_bf16(ah, wbl[t], acc, 0, 0, 0);
      acc = __builtin_amdgcn_mfma_f32_32x32x16_bf16(al, wbh[t], acc, 0, 0, 0);
    }
  }
  // ---- epilogue: C/D col=lane&31, row=(r&3)+8*(r>>2)+4*fq ----
  int col = lane & 31;
  int j = wv * 32 + col;
  float bv = EMBED ? bias[j] : 0.f;
#pragma unroll
  for (int r = 0; r < 16; r++) {
    int row = (r & 3) + 8 * (r >> 2) + 4 * fq;
    int node = node0 + row;
    if (node < N_NODES) {
      if (EMBED) {
        float v = acc[r] + bv;
        ushort_t h = f2bf(v);
        OutH[(size_t)node * D + j] = h;
        OutL[(size_t)node * D + j] = f2bf(v - bf2f(h));
      } else {
        // pre-scale by dinv[node] so aggregation needs no per-source weight
        OutT[(size_t)node * D + j] = f2bf(acc[r] * dinvp[node]);
      }
    }
  }
}

// ---------------- aggregation ----------------
// T is pre-scaled by dinv: out[d] = dinv[d]*(T[d] + sum_{s->d} T[s]) + b.
// One wave per node; lane handles packed cols {2l,2l+1}; edge loop unrolled x4.
template <bool RELU, bool SPLIT_OUT>
__global__ __launch_bounds__(256) void k_aggregate(
    const ushort_t* __restrict__ t, const int* __restrict__ row_start,
    const int* __restrict__ csr, const float* __restrict__ dinv,
    const float* __restrict__ bias, float* __restrict__ out_f,
    ushort_t* __restrict__ outH, ushort_t* __restrict__ outL) {
  int wave = threadIdx.x >> 6;
  int lane = threadIdx.x & 63;
  int node = blockIdx.x * 4 + wave;
  if (node >= N_NODES) return;
  const unsigned int* tu = (const unsigned int*)t;
  float ax, ay;
  {
    unsigned int u = tu[(size_t)node * 64 + lane];  // self-loop (pre-scaled)
    ax = bf2f((ushort_t)(u & 0xFFFF));
    ay = bf2f((ushort_t)(u >> 16));
  }
  int e0 = row_start[node], e1 = row_start[node + 1];
  for (int base = e0; base < e1; base += 64) {
    int cnt = min(64, e1 - base);
    int sidx = (lane < cnt) ? csr[base + lane] : 0;
    int i = 0;
    for (; i + 4 <= cnt; i += 4) {
      int s0 = __shfl(sidx, i);
      int s1 = __shfl(sidx, i + 1);
      int s2 = __shfl(sidx, i + 2);
      int s3 = __shfl(sidx, i + 3);
      unsigned int u0 = tu[(size_t)s0 * 64 + lane];
      unsigned int u1 = tu[(size_t)s1 * 64 + lane];
      unsigned int u2 = tu[(size_t)s2 * 64 + lane];
      unsigned int u3 = tu[(size_t)s3 * 64 + lane];
      ax += bf2f((ushort_t)(u0 & 0xFFFF));
      ay += bf2f((ushort_t)(u0 >> 16));
      ax += bf2f((ushort_t)(u1 & 0xFFFF));
      ay += bf2f((ushort_t)(u1 >> 16));
      ax += bf2f((ushort_t)(u2 & 0xFFFF));
      ay += bf2f((ushort_t)(u2 >> 16));
      ax += bf2f((ushort_t)(u3 & 0xFFFF));
      ay += bf2f((ushort_t)(u3 >> 16));
    }
    for (; i < cnt; i++) {
      int s = __shfl(sidx, i);
      unsigned int u = tu[(size_t)s * 64 + lane];
      ax += bf2f((ushort_t)(u & 0xFFFF));
      ay += bf2f((ushort_t)(u >> 16));
    }
  }
  float di = dinv[node];
  ax = di * ax + bias[2 * lane];
  ay = di * ay + bias[2 * lane + 1];
  if (RELU) {
    ax = fmaxf(ax, 0.f);
    ay = fmaxf(ay, 0.f);
  }
  if (SPLIT_OUT) {
    ushort2 h, l;
    h.x = f2bf(ax); l.x = f2bf(ax - bf2f(h.x));
    h.y = f2bf(ay); l.y = f2bf(ay - bf2f(h.y));
    *(ushort2*)&outH[(size_t)node * D + 2 * lane] = h;
    *(ushort2*)&outL[(size_t)node * D + 2 * lane] = l;
  } else {
    float2 o; o.x = ax; o.y = ay;
    *(float2*)&out_f[(size_t)node * D + 2 * lane] = o;
  }
}

extern "C" void kernel_launch(void* const* d_in, const int* in_sizes, int n_in,
                              void* d_out, int out_size, void* d_ws, size_t ws_size,
                              hipStream_t stream) {
  const int* tokens = (const int*)d_in[0];
  const int* edge = (const int*)d_in[1];  // [2][E]
  const void* embed = d_in[2];
  const void* Wn = d_in[3];
  const void* bn = d_in[4];
  const void* w1 = d_in[5];
  const void* b1 = d_in[6];
  const void* w2 = d_in[7];
  const void* b2 = d_in[8];
  float* out = (float*)d_out;  // fp32 output

  const int* src = edge;
  const int* dst = edge + N_EDGES;

  char* ws = (char*)d_ws;
  ushort_t* Xh = (ushort_t*)ws;                    // 12,800,000 B
  ushort_t* Xl = (ushort_t*)(ws + 12800000);       // 12,800,000 B
  ushort_t* T  = (ushort_t*)(ws + 25600000);       // 12,800,000 B
  float* dinv = (float*)(ws + 38400000);           // 200,000 B
  int* row_start = (int*)(ws + 38600064);          // 200,004 B (pad)
  int* degcur = (int*)(ws + 38800128);             // 400,000 B (deg | cursor)
  int* csr = (int*)(ws + 39200128);                // 2,400,000 B
  int* partial = (int*)(ws + 41600192);            // 196 B
  int* flags = (int*)(ws + 41600448);              // 28 B
  ushort_t* WnH = (ushort_t*)(ws + 41600512);      // 65,536 B
  ushort_t* WnL = (ushort_t*)(ws + 41666048);      // 65,536 B
  ushort_t* w1H = (ushort_t*)(ws + 41731584);      // 32,768 B
  ushort_t* w1L = (ushort_t*)(ws + 41764352);      // 32,768 B
  ushort_t* w2H = (ushort_t*)(ws + 41797120);      // 32,768 B
  ushort_t* w2L = (ushort_t*)(ws + 41829888);      // 32,768 B
  float* bias_ws = (float*)(ws + 41862656);        // 1,536 B
  const float* bnf = bias_ws;
  const float* b1f = bias_ws + 128;
  const float* b2f = bias_ws + 256;
  int* deg = degcur;
  int* cursor = degcur + N_NODES;

  const int GGRID = (N_NODES + 31) / 32;  // 1563

  // --- dtype detect + weight split + bias canonicalize ---
  k_detect<<<1, 256, 0, stream>>>(embed, Wn, bn, w1, b1, w2, b2, flags);
  k_split<<<(65920 + 255) / 256, 256, 0, stream>>>(
      Wn, w1, w2, bn, b1, b2, flags, WnH, WnL, w1H, w1L, w2H, w2L, bias_ws);

  // --- CSR build (one memset covers deg + cursor) ---
  hipMemsetAsync(degcur, 0, 2 * N_NODES * sizeof(int), stream);
  k_deg<<<(N_EDGES + 255) / 256, 256, 0, stream>>>(dst, deg);
  k_partial<<<N_CHUNKS, 256, 0, stream>>>(deg, partial);
  k_scan_part<<<1, 64, 0, stream>>>(partial, row_start);
  k_scan_final<<<N_CHUNKS, 256, 0, stream>>>(deg, partial, row_start, dinv);
  k_fill<<<(N_EDGES + 255) / 256, 256, 0, stream>>>(src, dst, row_start, cursor, csr);

  // --- x0 = embed[tokens] @ Wn^T + bn -> (Xh, Xl) ---
  k_gemm_v2<D_IN, true><<<GGRID, 256, 0, stream>>>(
      nullptr, nullptr, embed, tokens, flags, WnH, WnL, bnf, nullptr,
      Xh, Xl, nullptr);

  // --- conv1: T = (x0 @ w1^T)*dinv ; aggregate+b1+relu -> (Xh, Xl) ---
  k_gemm_v2<D, false><<<GGRID, 256, 0, stream>>>(
      Xh, Xl, nullptr, nullptr, nullptr, w1H, w1L, nullptr, dinv,
      nullptr, nullptr, T);
  k_aggregate<true, true><<<(N_NODES + 3) / 4, 256, 0, stream>>>(
      T, row_start, csr, dinv, b1f, nullptr, Xh, Xl);

  // --- conv2: T = (x1 @ w2^T)*dinv ; aggregate+b2 -> out (fp32) ---
  k_gemm_v2<D, false><<<GGRID, 256, 0, stream>>>(
      Xh, Xl, nullptr, nullptr, nullptr, w2H, w2L, nullptr, dinv,
      nullptr, nullptr, T);
  k_aggregate<false, false><<<(N_NODES + 3) / 4, 256, 0, stream>>>(
      T, row_start, csr, dinv, b2f, out, nullptr, nullptr);
}